// Round 3
// baseline (176.082 us; speedup 1.0000x reference)
//
#include <hip/hip_runtime.h>

// Native clang vector type — accepted by __builtin_nontemporal_{load,store},
// identical 16-byte layout to float4.
typedef float f4 __attribute__((ext_vector_type(4)));

// Fully fused, one dispatch, 4 lanes per ray (lane c owns output row c).
//
// Math (faithful to reference):
//   vec2skew stacks columns, so K = skew(v)^T = [[0,rz,-ry],[-rz,0,rx],[ry,-rx,0]]
//   n = |r| + 1e-15; A = sin(n)/n; B = (1-cos(n))/n^2
//   R = I + A*K + B*K^2, with K^2 = r r^T - |r|^2 I (exact, transpose-invariant)
//   c2w = [[R, t],[0,0,0,1]];  inv(c2w) = [[R^T, -R^T t],[0,0,0,1]]
//   out = E0[cam] @ inv(c2w)   → row i = (E0_row_i · T_cols, E0_row_i · u + e3)
//
// Memory behavior:
//  - cid[ray]: 4 adjacent lanes broadcast-read the same address (1 txn/16 rays).
//  - r,t: 6 scalar reads from 120 KB tables — L1/L2 resident, lane-broadcast.
//  - e0 row: float4 at 16 B; the 4 lanes of a ray cover one 64 B line.
//  - out: one float4 per lane, consecutive lanes → consecutive addresses,
//    nontemporal (write-once 128 MB stream; don't thrash L2).
// The ~x4 redundant Rodrigues per lane is ~5 µs of VALU device-wide — hidden
// under the 128 MB store stream.
__global__ __launch_bounds__(256) void fused_row_kernel(
        const float* __restrict__ r,
        const float* __restrict__ t,
        const float* __restrict__ e0,
        const int* __restrict__ cid,
        f4* __restrict__ out, int n4) {
    const int tid = blockIdx.x * blockDim.x + threadIdx.x;
    if (tid >= n4) return;
    const int ray = tid >> 2;
    const int c   = tid & 3;
    const int f   = cid[ray];

    const float rx = r[3 * f + 0], ry = r[3 * f + 1], rz = r[3 * f + 2];
    const float tx = t[3 * f + 0], ty = t[3 * f + 1], tz = t[3 * f + 2];

    const float s = rx * rx + ry * ry + rz * rz;
    const float n = sqrtf(s) + 1e-15f;
    const float sn = sinf(n), cn = cosf(n);
    const float A = sn / n;
    const float B = (1.0f - cn) / (n * n);

    // R = I + A*K + B*(r r^T - s I)
    const float R00 = 1.0f + B * (rx * rx - s);
    const float R01 =  A * rz + B * (rx * ry);
    const float R02 = -A * ry + B * (rx * rz);
    const float R10 = -A * rz + B * (rx * ry);
    const float R11 = 1.0f + B * (ry * ry - s);
    const float R12 =  A * rx + B * (ry * rz);
    const float R20 =  A * ry + B * (rx * rz);
    const float R21 = -A * rx + B * (ry * rz);
    const float R22 = 1.0f + B * (rz * rz - s);

    // T = R^T, u = -R^T t
    const float T00 = R00, T01 = R10, T02 = R20;
    const float T10 = R01, T11 = R11, T12 = R21;
    const float T20 = R02, T21 = R12, T22 = R22;
    const float u0 = -(T00 * tx + T01 * ty + T02 * tz);
    const float u1 = -(T10 * tx + T11 * ty + T12 * tz);
    const float u2 = -(T20 * tx + T21 * ty + T22 * tz);

    // This lane's E0 row (16 B, 64 B line shared by the ray's 4 lanes).
    const f4 e = *reinterpret_cast<const f4*>(e0 + 16 * f + 4 * c);

    f4 m;
    m.x = e.x * T00 + e.y * T10 + e.z * T20;
    m.y = e.x * T01 + e.y * T11 + e.z * T21;
    m.z = e.x * T02 + e.y * T12 + e.z * T22;
    m.w = e.x * u0 + e.y * u1 + e.z * u2 + e.w;

    __builtin_nontemporal_store(m, out + tid);
}

extern "C" void kernel_launch(void* const* d_in, const int* in_sizes, int n_in,
                              void* d_out, int out_size, void* d_ws, size_t ws_size,
                              hipStream_t stream) {
    const float* r  = (const float*)d_in[0];   // (NF, 3)
    const float* t  = (const float*)d_in[1];   // (NF, 3)
    const float* e0 = (const float*)d_in[2];   // (NF, 4, 4)
    const int*  cid = (const int*)d_in[3];     // (NR,)
    float* out = (float*)d_out;                // (NR, 4, 4)

    const int nr = in_sizes[3];
    const int n4 = nr * 4;                     // one thread per output row
    const int threads = 256;
    const int blocks = (n4 + threads - 1) / threads;
    fused_row_kernel<<<blocks, threads, 0, stream>>>(
        r, t, e0, cid, (f4*)out, n4);
}